// Round 3
// baseline (2967.100 us; speedup 1.0000x reference)
//
#include <hip/hip_runtime.h>

typedef _Float16 f16;
typedef _Float16 f16x2 __attribute__((ext_vector_type(2)));
typedef _Float16 f16x8 __attribute__((ext_vector_type(8)));
typedef __fp16   h16x2 __attribute__((ext_vector_type(2)));
typedef float    f32x4 __attribute__((ext_vector_type(4)));

#define B_ 32
#define S_ 2048
#define E_ 256
#define H_ 256
#define M_ (B_ * S_)   // 65536

union U32F2 { unsigned int u; f16x2 h; h16x2 g; };

__device__ __forceinline__ float fdot2f(f16x2 a, f16x2 b, float c) {
#if __has_builtin(__builtin_amdgcn_fdot2)
  return __builtin_amdgcn_fdot2(a, b, c, false);
#else
  return c + (float)a.x * (float)b.x + (float)a.y * (float)b.y;
#endif
}

__device__ __forceinline__ float fast_exp2(float x) {
#if __has_builtin(__builtin_amdgcn_exp2f)
  return __builtin_amdgcn_exp2f(x);
#else
  return exp2f(x);
#endif
}
__device__ __forceinline__ float fast_rcp(float x) {
#if __has_builtin(__builtin_amdgcn_rcpf)
  return __builtin_amdgcn_rcpf(x);
#else
  return 1.0f / x;
#endif
}

__device__ __forceinline__ float sigm(float x) {
  float e = fast_exp2(-1.4426950408889634f * x);
  return fast_rcp(1.0f + e);
}
__device__ __forceinline__ float tanh_fast(float x) {
  x = fminf(15.0f, fmaxf(-15.0f, x));
  float e = fast_exp2(2.8853900817779268f * x); // exp(2x)
  return (e - 1.0f) * fast_rcp(e + 1.0f);
}

// ---------------------------------------------------------------------------
// Kernel A: Xg[g][m][h] = (x @ W_g) in f16, g in {z,r,h}, m = b*S + s.
// Tile: 64 rows x 64 cols per wg, 4 waves (each wave 16 rows x 64 cols).
// W^T slice staged in LDS [64][264] f16 (264*2=528B rows: only 2-way bank
// aliasing, which is free). A-frags read straight from global (f32->f16).
// ---------------------------------------------------------------------------
__global__ __launch_bounds__(256, 4) void proj_gemm(
    const float* __restrict__ x, const float* __restrict__ Wz,
    const float* __restrict__ Wr, const float* __restrict__ Wh,
    f16* __restrict__ Xg) {
  __shared__ __align__(16) f16 Wl[64][264];
  const int tid = threadIdx.x;
  const int wv = tid >> 6;
  const int ln = tid & 63;
  const int M0 = blockIdx.x * 64;
  const int nb = blockIdx.y;           // 0..11
  const int gate = nb >> 2;            // 0,1,2
  const int c0 = (nb & 3) * 64;        // col base within gate
  const float* W = (gate == 0) ? Wz : (gate == 1 ? Wr : Wh);

  // stage W^T: Wl[c][k] = W[k][c0+c]
#pragma unroll
  for (int i = 0; i < 64; ++i) {
    int e = i * 256 + tid;       // 16384 elements
    int cl = e & 63;
    int k = e >> 6;
    Wl[cl][k] = (f16)W[(size_t)k * H_ + c0 + cl];
  }
  __syncthreads();

  const int row = M0 + wv * 16 + (ln & 15);
  const int kg = (ln >> 4) * 8;
  f32x4 acc0 = {0.f, 0.f, 0.f, 0.f};
  f32x4 acc1 = {0.f, 0.f, 0.f, 0.f};
  f32x4 acc2 = {0.f, 0.f, 0.f, 0.f};
  f32x4 acc3 = {0.f, 0.f, 0.f, 0.f};

#pragma unroll
  for (int kk = 0; kk < 8; ++kk) {
    const int k0 = kk * 32;
    const float* ap = x + (size_t)row * E_ + k0 + kg;
    float4 a0 = *(const float4*)ap;
    float4 a1 = *(const float4*)(ap + 4);
    f16x8 af = {(f16)a0.x, (f16)a0.y, (f16)a0.z, (f16)a0.w,
                (f16)a1.x, (f16)a1.y, (f16)a1.z, (f16)a1.w};
    f16x8 b0 = *(const f16x8*)&Wl[0 * 16 + (ln & 15)][k0 + kg];
    f16x8 b1 = *(const f16x8*)&Wl[1 * 16 + (ln & 15)][k0 + kg];
    f16x8 b2 = *(const f16x8*)&Wl[2 * 16 + (ln & 15)][k0 + kg];
    f16x8 b3 = *(const f16x8*)&Wl[3 * 16 + (ln & 15)][k0 + kg];
    acc0 = __builtin_amdgcn_mfma_f32_16x16x32_f16(af, b0, acc0, 0, 0, 0);
    acc1 = __builtin_amdgcn_mfma_f32_16x16x32_f16(af, b1, acc1, 0, 0, 0);
    acc2 = __builtin_amdgcn_mfma_f32_16x16x32_f16(af, b2, acc2, 0, 0, 0);
    acc3 = __builtin_amdgcn_mfma_f32_16x16x32_f16(af, b3, acc3, 0, 0, 0);
  }

  f16* outg = Xg + (size_t)gate * ((size_t)M_ * H_);
  const int rbase = M0 + wv * 16 + (ln >> 4) * 4;
#define EPI(NT, ACC)                                                       \
  {                                                                        \
    const int cc = c0 + NT * 16 + (ln & 15);                               \
    outg[(size_t)(rbase + 0) * H_ + cc] = (f16)ACC[0];                     \
    outg[(size_t)(rbase + 1) * H_ + cc] = (f16)ACC[1];                     \
    outg[(size_t)(rbase + 2) * H_ + cc] = (f16)ACC[2];                     \
    outg[(size_t)(rbase + 3) * H_ + cc] = (f16)ACC[3];                     \
  }
  EPI(0, acc0) EPI(1, acc1) EPI(2, acc2) EPI(3, acc3)
#undef EPI
}

// ---------------------------------------------------------------------------
// Kernel B: the recurrence. 32 wgs (one per batch), 512 threads (8 waves).
// Lane owns column c = wave*32 + (lane&31); half hi = lane>>5 covers K rows
// [hi*128, hi*128+128). All of Uz/Ur/Uh held in VGPRs as packed f16 pairs
// (192 regs/lane). h and r*h exchanged as packed f16 pairs via 1KB LDS.
// 2 __syncthreads per step; zero inter-workgroup communication.
// ---------------------------------------------------------------------------
__global__ __launch_bounds__(512, 2) void gru_rec(
    const f16* __restrict__ Xg, const float* __restrict__ h0,
    const float* __restrict__ Uz, const float* __restrict__ Ur,
    const float* __restrict__ Uh, float* __restrict__ out) {
  __shared__ uint4 h2v[32];    // 128 packed f16 pairs of h
  __shared__ uint4 rh2v[32];   // 128 packed f16 pairs of r*h
  const int b = blockIdx.x;
  const int tid = threadIdx.x;
  const int wv = tid >> 6;
  const int ln = tid & 63;
  const int c = wv * 32 + (ln & 31);
  const int hi = ln >> 5;              // K-half
  const bool owner = (hi == 0);

  // ---- preload weights into registers (packed f16 pairs along K) ----
  f16x2 wz[64], wr[64], wh[64];
  {
    const int rb = hi * 128;
#pragma unroll
    for (int j = 0; j < 64; ++j) {
      const size_t o0 = (size_t)(rb + 2 * j) * H_ + c;
      const size_t o1 = o0 + H_;
      wz[j] = f16x2{(f16)Uz[o0], (f16)Uz[o1]};
      wr[j] = f16x2{(f16)Ur[o0], (f16)Ur[o1]};
      wh[j] = f16x2{(f16)Uh[o0], (f16)Uh[o1]};
    }
  }

  // ---- init h ----
  float h_reg = 0.f;
  if (owner) h_reg = h0[b * H_ + c];
  {
    float hn = __shfl_xor(h_reg, 1);
    if (owner && !(ln & 1)) {
      U32F2 p; p.g = __builtin_amdgcn_cvt_pkrtz(h_reg, hn);
      ((unsigned int*)h2v)[c >> 1] = p.u;
    }
  }
  __syncthreads();

  const f16* xz = Xg + (size_t)b * ((size_t)S_ * H_) + c;
  const f16* xr = xz + (size_t)M_ * H_;
  const f16* xh = xr + (size_t)M_ * H_;
  float* outp = out + (size_t)b * ((size_t)S_ * H_) + c;

  // prefetch x values for t=0 (kept as f16, converted at use)
  f16 pz = xz[0], pr = xr[0], ph = xh[0];

  for (int t = 0; t < S_; ++t) {
    const float xzc = (float)pz, xrc = (float)pr, xhc = (float)ph;
    {  // prefetch t+1
      const int t2 = (t + 1 < S_) ? (t + 1) : t;
      const size_t off = (size_t)t2 * H_;
      pz = xz[off]; pr = xr[off]; ph = xh[off];
    }

    // ---- phase 1: z and r dots over h ----
    float az = 0.f, ar = 0.f;
#pragma unroll
    for (int q = 0; q < 16; ++q) {
      uint4 hv = h2v[hi * 16 + q];
      U32F2 p0, p1, p2, p3;
      p0.u = hv.x; p1.u = hv.y; p2.u = hv.z; p3.u = hv.w;
      az = fdot2f(wz[4 * q + 0], p0.h, az);
      az = fdot2f(wz[4 * q + 1], p1.h, az);
      az = fdot2f(wz[4 * q + 2], p2.h, az);
      az = fdot2f(wz[4 * q + 3], p3.h, az);
      ar = fdot2f(wr[4 * q + 0], p0.h, ar);
      ar = fdot2f(wr[4 * q + 1], p1.h, ar);
      ar = fdot2f(wr[4 * q + 2], p2.h, ar);
      ar = fdot2f(wr[4 * q + 3], p3.h, ar);
    }
    az += __shfl_xor(az, 32);
    ar += __shfl_xor(ar, 32);

    float z_s = 0.f, rh = 0.f;
    if (owner) {
      z_s = sigm(az + xzc);
      float rr = sigm(ar + xrc);
      rh = rr * h_reg;
    }
    {
      float rhn = __shfl_xor(rh, 1);
      if (owner && !(ln & 1)) {
        U32F2 p; p.g = __builtin_amdgcn_cvt_pkrtz(rh, rhn);
        ((unsigned int*)rh2v)[c >> 1] = p.u;
      }
    }
    __syncthreads();

    // ---- phase 2: candidate dot over r*h ----
    float ah = 0.f;
#pragma unroll
    for (int q = 0; q < 16; ++q) {
      uint4 rv = rh2v[hi * 16 + q];
      U32F2 p0, p1, p2, p3;
      p0.u = rv.x; p1.u = rv.y; p2.u = rv.z; p3.u = rv.w;
      ah = fdot2f(wh[4 * q + 0], p0.h, ah);
      ah = fdot2f(wh[4 * q + 1], p1.h, ah);
      ah = fdot2f(wh[4 * q + 2], p2.h, ah);
      ah = fdot2f(wh[4 * q + 3], p3.h, ah);
    }
    ah += __shfl_xor(ah, 32);

    if (owner) {
      float ht = tanh_fast(ah + xhc);
      h_reg = h_reg + z_s * (ht - h_reg);     // (1-z)h + z*h~
      outp[(size_t)t * H_] = h_reg;
    }
    {
      float hn = __shfl_xor(h_reg, 1);
      if (owner && !(ln & 1)) {
        U32F2 p; p.g = __builtin_amdgcn_cvt_pkrtz(h_reg, hn);
        ((unsigned int*)h2v)[c >> 1] = p.u;
      }
    }
    __syncthreads();
  }
}

extern "C" void kernel_launch(void* const* d_in, const int* in_sizes, int n_in,
                              void* d_out, int out_size, void* d_ws,
                              size_t ws_size, hipStream_t stream) {
  const float* x  = (const float*)d_in[0];
  const float* h0 = (const float*)d_in[1];
  const float* Wz = (const float*)d_in[2];
  const float* Uz = (const float*)d_in[3];
  const float* Wr = (const float*)d_in[4];
  const float* Ur = (const float*)d_in[5];
  const float* Wh = (const float*)d_in[6];
  const float* Uh = (const float*)d_in[7];
  float* out = (float*)d_out;

  const size_t need = (size_t)3 * M_ * H_ * sizeof(f16);  // 100.7 MB
  if (ws_size < need) return;  // fail loudly via absmax rather than corrupt
  f16* Xg = (f16*)d_ws;

  proj_gemm<<<dim3(M_ / 64, 12), 256, 0, stream>>>(x, Wz, Wr, Wh, Xg);
  gru_rec<<<dim3(B_), 512, 0, stream>>>(Xg, h0, Uz, Ur, Uh, out);
}